// Round 5
// baseline (536.763 us; speedup 1.0000x reference)
//
#include <hip/hip_runtime.h>

// SparseAttention MI355X — round 5 (= round 4 resubmit; never ran due to GPU timeout).
// Screen with 3-pass split-bf16 MFMA (err sigma ~4e-6 scaled); pool ratchet keeps
// everything >= (approx 64th - MARGIN) so the true top-64 is always in the pool;
// final stage rescores only the boundary band in f64 (exact) so the selected set
// matches the fp64/fp32 reference deterministically.

#define QN 2048
#define KN 2048
#define DN 256
#define NEGV (-1000000.0f)
#define PC 128
#define CAP 200u
#define CAPP 201
#define TRIG 72u
#define MARGIN 3e-4f

typedef __attribute__((ext_vector_type(8))) short short8;
typedef __attribute__((ext_vector_type(4))) float f32x4;

union U4S8 { uint4 u; short8 s; };

__device__ __forceinline__ unsigned sortkey(unsigned b) {
  return b ^ (unsigned)((((int)b) >> 31) | 0x80000000u);
}
__device__ __forceinline__ float keytofloat(unsigned k) {
  unsigned b = (k & 0x80000000u) ? (k ^ 0x80000000u) : ~k;
  return __uint_as_float(b);
}
__device__ __forceinline__ unsigned long long sortkey64(double d) {
  long long b = __double_as_longlong(d);
  return (unsigned long long)(b ^ ((b >> 63) | 0x8000000000000000LL));
}
__device__ __forceinline__ unsigned pack_hi(unsigned a, unsigned b) {
  return (b & 0xFFFF0000u) | (a >> 16);
}

// split 8 floats into hi/lo bf16 (truncation split)
__device__ __forceinline__ void split8(const float4& x0, const float4& x1,
                                       short8& hi8, short8& lo8) {
  float f[8] = {x0.x, x0.y, x0.z, x0.w, x1.x, x1.y, x1.z, x1.w};
  unsigned hw[4], lw[4];
#pragma unroll
  for (int i = 0; i < 4; ++i) {
    unsigned a = __float_as_uint(f[2 * i]);
    unsigned b = __float_as_uint(f[2 * i + 1]);
    hw[i] = pack_hi(a, b);
    float ra = f[2 * i]     - __uint_as_float(a & 0xFFFF0000u);
    float rb = f[2 * i + 1] - __uint_as_float(b & 0xFFFF0000u);
    lw[i] = pack_hi(__float_as_uint(ra), __float_as_uint(rb));
  }
  U4S8 h, l;
  h.u = make_uint4(hw[0], hw[1], hw[2], hw[3]);
  l.u = make_uint4(lw[0], lw[1], lw[2], lw[3]);
  hi8 = h.s;
  lo8 = l.s;
}

__global__ __launch_bounds__(256, 2) void sparse_attn(const float* __restrict__ Q,
                                                      const float* __restrict__ K,
                                                      const float* __restrict__ V,
                                                      const int* __restrict__ vlens,
                                                      float* __restrict__ out) {
  __shared__ float S[32][PC];        // 16 KB
  __shared__ uint2 pool[32][CAPP];   // 50.25 KB
  __shared__ unsigned cnt[32];
  __shared__ unsigned Lb[32];
  __shared__ unsigned nqs[32];
  __shared__ float rden[32];

  const unsigned tid = threadIdx.x;
  const unsigned w = tid >> 6, lane = tid & 63u;
  const unsigned lm = lane & 15u, lg = lane >> 4;
  const unsigned bid = blockIdx.x;
  const unsigned b = bid >> 6, qt = bid & 63u;
  const int vlen = vlens[b];
  const unsigned long long below = (1ull << lane) - 1ull;

  // ---------------- vlen == 0: uniform softmax -> column mean of V
  if (vlen == 0) {
    float* PS = (float*)&pool[0][0];  // 12864 floats, need 8448
    unsigned g = tid >> 3, ds = tid & 7u;
    float4 s[8];
#pragma unroll
    for (int j = 0; j < 8; ++j) s[j] = make_float4(0.f, 0.f, 0.f, 0.f);
    const float* Vb = V + (size_t)b * KN * DN;
    for (int i = 0; i < 64; ++i) {
      const float* vr = Vb + (size_t)(g * 64u + i) * DN + ds * 32u;
#pragma unroll
      for (int j = 0; j < 8; ++j) {
        float4 vv = *(const float4*)(vr + j * 4);
        s[j].x += vv.x; s[j].y += vv.y; s[j].z += vv.z; s[j].w += vv.w;
      }
    }
#pragma unroll
    for (int j = 0; j < 8; ++j)
      *(float4*)&PS[g * 256u + ds * 32u + j * 4] = s[j];
    __syncthreads();
    float mval = 0.f;
    for (int g2 = 0; g2 < 32; ++g2) mval += PS[g2 * 256 + tid];
    PS[8192 + tid] = mval * (1.0f / 2048.0f);
    __syncthreads();
    unsigned row = tid >> 3;
    float* op = out + ((size_t)(b * QN + qt * 32u + row)) * DN + ds * 32u;
#pragma unroll
    for (int j = 0; j < 8; ++j)
      *(float4*)(op + j * 4) = *(const float4*)&PS[8192 + ds * 32u + j * 4];
    return;
  }

  if (tid < 32) { cnt[tid] = 0u; Lb[tid] = 0u; }
  __syncthreads();

  // ---------------- Q fragments (hi/lo split) in registers
  short8 qh[2][8], ql[2][8];
#pragma unroll
  for (int rt = 0; rt < 2; ++rt) {
    const float* qrow = Q + ((size_t)(b * QN + qt * 32u + rt * 16u + lm)) * DN;
#pragma unroll
    for (int c = 0; c < 8; ++c) {
      const float* src = qrow + c * 32u + lg * 8u;
      float4 x0 = *(const float4*)(src);
      float4 x1 = *(const float4*)(src + 4);
      split8(x0, x1, qh[rt][c], ql[rt][c]);
    }
  }

  const float* Kb = K + (size_t)b * KN * DN;
  unsigned nparts = ((unsigned)vlen + (PC - 1)) / PC;
  if (nparts > 16u) nparts = 16u;

  for (unsigned p = 0; p < nparts; ++p) {
    f32x4 acc[2][2];
#pragma unroll
    for (int rt = 0; rt < 2; ++rt)
#pragma unroll
      for (int j = 0; j < 2; ++j) acc[rt][j] = (f32x4){0.f, 0.f, 0.f, 0.f};

    unsigned colbase = p * PC + w * 32u;
#pragma unroll
    for (int c = 0; c < 8; ++c) {
#pragma unroll
      for (int j = 0; j < 2; ++j) {
        const float* src = Kb + (size_t)(colbase + j * 16u + lm) * DN + c * 32u + lg * 8u;
        float4 x0 = *(const float4*)(src);
        float4 x1 = *(const float4*)(src + 4);
        short8 kh, kl;
        split8(x0, x1, kh, kl);
        acc[0][j] = __builtin_amdgcn_mfma_f32_16x16x32_bf16(qh[0][c], kh, acc[0][j], 0, 0, 0);
        acc[1][j] = __builtin_amdgcn_mfma_f32_16x16x32_bf16(qh[1][c], kh, acc[1][j], 0, 0, 0);
        acc[0][j] = __builtin_amdgcn_mfma_f32_16x16x32_bf16(ql[0][c], kh, acc[0][j], 0, 0, 0);
        acc[1][j] = __builtin_amdgcn_mfma_f32_16x16x32_bf16(ql[1][c], kh, acc[1][j], 0, 0, 0);
        acc[0][j] = __builtin_amdgcn_mfma_f32_16x16x32_bf16(qh[0][c], kl, acc[0][j], 0, 0, 0);
        acc[1][j] = __builtin_amdgcn_mfma_f32_16x16x32_bf16(qh[1][c], kl, acc[1][j], 0, 0, 0);
      }
    }

    // scale + mask -> S  (D layout: col=lane&15, row=(lane>>4)*4+reg)
#pragma unroll
    for (int rt = 0; rt < 2; ++rt)
#pragma unroll
      for (int j = 0; j < 2; ++j)
#pragma unroll
        for (int r = 0; r < 4; ++r) {
          unsigned row = rt * 16u + lg * 4u + r;
          unsigned col = w * 32u + j * 16u + lm;
          float v = acc[rt][j][r] * 0.0625f;
          if (p * PC + col >= (unsigned)vlen) v = NEGV;
          S[row][col] = v;
        }
    __syncthreads();

    // per-row insert (wave w owns rows w*8..w*8+7)
    for (int rr = 0; rr < 8; ++rr) {
      unsigned row = w * 8u + rr;
      unsigned L = Lb[row];
#pragma unroll
      for (int i = 0; i < 2; ++i) {
        unsigned cidx = lane + 64u * i;
        float v = S[row][cidx];
        unsigned kk = sortkey(__float_as_uint(v));
        bool qual = (v != NEGV) && (kk >= L);
        unsigned long long mask = __ballot(qual);
        if (mask) {
          int ldr = __ffsll((unsigned long long)mask) - 1;
          unsigned base = 0;
          if ((int)lane == ldr) base = atomicAdd(&cnt[row], (unsigned)__popcll(mask));
          base = __shfl(base, ldr);
          unsigned pos = base + (unsigned)__popcll(mask & below);
          if (qual && pos < CAP)
            pool[row][pos] = make_uint2(__float_as_uint(v), p * PC + cidx);
        }
      }
      // ratchet + compact with MARGIN (true top-64 never dropped)
      unsigned n = cnt[row]; if (n > CAP) n = CAP;
      if (n > TRIG) {
        bool val[4]; uint2 e[4]; unsigned key[4]; float f[4];
#pragma unroll
        for (int t = 0; t < 4; ++t) {
          unsigned idx = lane + 64u * t;
          val[t] = idx < n;
          e[t] = val[t] ? pool[row][idx] : make_uint2(0u, 0u);
          key[t] = val[t] ? sortkey(e[t].x) : 0u;
          f[t] = val[t] ? __uint_as_float(e[t].x) : -3.4e38f;
        }
        unsigned lo = 0u, hi = 0xFFFFFFF0u;
        for (int it = 0; it < 34 && lo < hi; ++it) {
          unsigned mid = lo + ((hi - lo + 1u) >> 1);
          int c = 0;
#pragma unroll
          for (int t = 0; t < 4; ++t) c += (int)__popcll(__ballot(key[t] >= mid));
          if (c == 64) { lo = mid; break; }
          if (c > 64) lo = mid; else hi = mid - 1u;
        }
        float thrf = keytofloat(lo) - MARGIN;
        unsigned nn = 0;
#pragma unroll
        for (int t = 0; t < 4; ++t) {
          bool q = val[t] && (f[t] >= thrf);
          unsigned long long mk = __ballot(q);
          if (q) pool[row][nn + (unsigned)__popcll(mk & below)] = e[t];
          nn += (unsigned)__popcll(mk);
        }
        if (lane == 0) { cnt[row] = nn; Lb[row] = sortkey(__float_as_uint(thrf)); }
      }
    }
    __syncthreads();
  }

  // ---------------- final: exact selection (f64 boundary band), softmax
  for (int rr = 0; rr < 8; ++rr) {
    unsigned row = w * 8u + rr;
    unsigned n = cnt[row]; if (n > CAP) n = CAP;
    bool val[4]; uint2 e[4]; unsigned key[4]; float f[4];
#pragma unroll
    for (int t = 0; t < 4; ++t) {
      unsigned idx = lane + 64u * t;
      val[t] = idx < n;
      e[t] = val[t] ? pool[row][idx] : make_uint2(0u, 0u);
      key[t] = val[t] ? sortkey(e[t].x) : 0u;
      f[t] = val[t] ? __uint_as_float(e[t].x) : -3.4e38f;
    }
    bool sel[4];
    if (n > 64u) {
      unsigned lo = 0u, hi = 0xFFFFFFF0u;
      for (int it = 0; it < 34 && lo < hi; ++it) {
        unsigned mid = lo + ((hi - lo + 1u) >> 1);
        int c = 0;
#pragma unroll
        for (int t = 0; t < 4; ++t) c += (int)__popcll(__ballot(key[t] >= mid));
        if (c == 64) { lo = mid; break; }
        if (c > 64) lo = mid; else hi = mid - 1u;
      }
      float m64f = keytofloat(lo);
      float hi_thr = m64f + MARGIN, lo_thr = m64f - MARGIN;
      bool def_[4], band[4];
      int ndef = 0;
#pragma unroll
      for (int t = 0; t < 4; ++t) {
        def_[t] = val[t] && (f[t] >= hi_thr);
        band[t] = val[t] && !def_[t] && (f[t] >= lo_thr);
        ndef += (int)__popcll(__ballot(def_[t]));
      }
      // exact f64 rescore of band elements (cooperative: 64 lanes x 4 dims)
      const float* qrow = Q + ((size_t)(b * QN + qt * 32u + row)) * DN;
      float4 qv = *(const float4*)(qrow + lane * 4u);
      unsigned long long K64[4] = {0ull, 0ull, 0ull, 0ull};
#pragma unroll
      for (int t = 0; t < 4; ++t) {
        unsigned long long mk = __ballot(band[t]);
        while (mk) {
          int src = __ffsll(mk) - 1;
          mk &= mk - 1ull;
          unsigned col = (unsigned)__shfl((int)e[t].y, src);
          const float4 kv = *(const float4*)(Kb + (size_t)col * DN + lane * 4u);
          double s = fma((double)qv.x, (double)kv.x,
                     fma((double)qv.y, (double)kv.y,
                     fma((double)qv.z, (double)kv.z,
                         (double)qv.w * (double)kv.w)));
#pragma unroll
          for (int off = 32; off > 0; off >>= 1) s += __shfl_xor(s, off);
          if ((int)lane == src) K64[t] = sortkey64(s * 0.0625);
        }
      }
      bool rem[4];
#pragma unroll
      for (int t = 0; t < 4; ++t) { sel[t] = def_[t]; rem[t] = band[t]; }
      int sc = ndef;
      while (sc < 64) {
        unsigned long long mv = 0ull;
#pragma unroll
        for (int t = 0; t < 4; ++t)
          if (rem[t] && K64[t] > mv) mv = K64[t];
#pragma unroll
        for (int off = 32; off > 0; off >>= 1) {
          unsigned long long o = __shfl_xor(mv, off);
          if (o > mv) mv = o;
        }
        bool picked = false;
#pragma unroll
        for (int t = 0; t < 4; ++t) {
          if (!picked) {
            unsigned long long mk = __ballot(rem[t] && K64[t] == mv);
            if (mk) {
              if ((int)lane == __ffsll(mk) - 1) { rem[t] = false; sel[t] = true; }
              picked = true;
            }
          }
        }
        ++sc;
        if (!picked) break;  // safety (cannot happen: band >= need)
      }
    } else {
#pragma unroll
      for (int t = 0; t < 4; ++t) sel[t] = val[t];
    }

    // softmax over selected (approx scores; continuous -> error negligible)
    float mx = -3.4e38f;
#pragma unroll
    for (int t = 0; t < 4; ++t) if (val[t]) mx = fmaxf(mx, f[t]);
#pragma unroll
    for (int off = 32; off > 0; off >>= 1) mx = fmaxf(mx, __shfl_xor(mx, off));
    float wv[4];
    float zs = 0.f;
#pragma unroll
    for (int t = 0; t < 4; ++t) {
      wv[t] = sel[t] ? expf(f[t] - mx) : 0.f;
      zs += wv[t];
    }
#pragma unroll
    for (int off = 32; off > 0; off >>= 1) zs += __shfl_xor(zs, off);

    unsigned nn = 0;
#pragma unroll
    for (int t = 0; t < 4; ++t) {
      unsigned long long mk = __ballot(sel[t]);
      if (sel[t])
        pool[row][nn + (unsigned)__popcll(mk & below)] =
            make_uint2(__float_as_uint(wv[t]), e[t].y);
      nn += (unsigned)__popcll(mk);
    }
    if (lane == 0) { nqs[row] = nn; rden[row] = 1.0f / zs; }
  }
  __syncthreads();

  // ---------------- gather: 8 threads per row, 32 floats each
  {
    unsigned grow = tid >> 3, gds = tid & 7u;
    unsigned gnq = nqs[grow];
    float rd = rden[grow];
    float4 a[8];
#pragma unroll
    for (int j = 0; j < 8; ++j) a[j] = make_float4(0.f, 0.f, 0.f, 0.f);
    const float* Vb = V + (size_t)b * KN * DN;
    for (unsigned ei = 0; ei < gnq; ++ei) {
      uint2 pe = pool[grow][ei];
      float wvv = __uint_as_float(pe.x);
      const float* vr = Vb + (size_t)pe.y * DN + gds * 32u;
#pragma unroll
      for (int j = 0; j < 8; ++j) {
        float4 vv = *(const float4*)(vr + j * 4);
        a[j].x = fmaf(wvv, vv.x, a[j].x);
        a[j].y = fmaf(wvv, vv.y, a[j].y);
        a[j].z = fmaf(wvv, vv.z, a[j].z);
        a[j].w = fmaf(wvv, vv.w, a[j].w);
      }
    }
    float* op = out + ((size_t)(b * QN + qt * 32u + grow)) * DN + gds * 32u;
#pragma unroll
    for (int j = 0; j < 8; ++j) {
      float4 r = make_float4(a[j].x * rd, a[j].y * rd, a[j].z * rd, a[j].w * rd);
      *(float4*)(op + j * 4) = r;
    }
  }
}

extern "C" void kernel_launch(void* const* d_in, const int* in_sizes, int n_in,
                              void* d_out, int out_size, void* d_ws, size_t ws_size,
                              hipStream_t stream) {
  (void)in_sizes; (void)n_in; (void)out_size; (void)d_ws; (void)ws_size;
  const float* Q = (const float*)d_in[0];
  const float* K = (const float*)d_in[1];
  const float* V = (const float*)d_in[2];
  const int* vl = (const int*)d_in[3];
  float* out = (float*)d_out;
  sparse_attn<<<dim3(512), dim3(256), 0, stream>>>(Q, K, V, vl, out);
}